// Round 2
// baseline (229.091 us; speedup 1.0000x reference)
//
#include <hip/hip_runtime.h>

// Problem: inputs (4096, 8192) f32.
// out[i][j] = max over s in {0,2048,4096,6144} of in[i][(j-s) mod 8192]
//           = max_k in[i][(j mod 2048) + 2048*k],  k=0..3
// => compute 2048-wide per-row max of the 4 column quarters, write it 4x.

#define ROWS 4096
#define L    8192
#define Q    2048          // L/4
#define QV   (Q / 4)       // 512 float4 per quarter-row

__global__ __launch_bounds__(256) void dense_max_pool_kernel(
    const float* __restrict__ in, float* __restrict__ out) {
    // one thread per float4 of the reduced vector: ROWS * QV threads total
    unsigned idx = blockIdx.x * blockDim.x + threadIdx.x;   // < ROWS*QV = 2M
    unsigned row = idx >> 9;          // / QV (512)
    unsigned q   = idx & (QV - 1);    // % QV

    const float4* in4  = (const float4*)in;
    float4*       out4 = (float4*)out;

    size_t base = (size_t)row * (L / 4) + q;   // float4 index of row start + q

    float4 a = in4[base];
    float4 b = in4[base + QV];
    float4 c = in4[base + 2 * QV];
    float4 d = in4[base + 3 * QV];

    float4 m;
    m.x = fmaxf(fmaxf(a.x, b.x), fmaxf(c.x, d.x));
    m.y = fmaxf(fmaxf(a.y, b.y), fmaxf(c.y, d.y));
    m.z = fmaxf(fmaxf(a.z, b.z), fmaxf(c.z, d.z));
    m.w = fmaxf(fmaxf(a.w, b.w), fmaxf(c.w, d.w));

    out4[base]          = m;
    out4[base + QV]     = m;
    out4[base + 2 * QV] = m;
    out4[base + 3 * QV] = m;
}

extern "C" void kernel_launch(void* const* d_in, const int* in_sizes, int n_in,
                              void* d_out, int out_size, void* d_ws, size_t ws_size,
                              hipStream_t stream) {
    const float* in = (const float*)d_in[0];
    float* out = (float*)d_out;

    const int total_threads = ROWS * QV;         // 2,097,152
    const int block = 256;
    const int grid = total_threads / block;      // 8192

    dense_max_pool_kernel<<<grid, block, 0, stream>>>(in, out);
}